// Round 3
// baseline (665.560 us; speedup 1.0000x reference)
//
#include <hip/hip_runtime.h>

#define B 32
#define N 1024
#define E 32768
#define F 32
#define C 10
#define NC (N + C)   // 1034
#define NF (N * F)   // 32768

// ws layout (float offsets)
#define WS_XS    0
#define WS_DIS   32768
#define WS_G     65536
#define WS_ZX    98304
#define WS_ZAIN  131392
#define WS_ZA    164480
// total 197248 floats = 771 KB

__device__ __forceinline__ float wave_sum(float v) {
#pragma unroll
  for (int off = 32; off; off >>= 1) v += __shfl_xor(v, off, 64);
  return v;
}

// Reduce 32 per-lane partial arrays across 64 lanes; lane l (and l+32) returns
// the full sum for b = (l & 31). All indices compile-time (no scratch).
__device__ __forceinline__ float reduce32_distribute(float (&v)[32], int lane) {
#pragma unroll
  for (int i = 0; i < 32; ++i) v[i] += __shfl_xor(v[i], 32, 64);
  float a[16];
  {
    bool hi = (lane & 16) != 0;
#pragma unroll
    for (int i = 0; i < 16; ++i) {
      float mine = hi ? v[i + 16] : v[i];
      float theirs = hi ? v[i] : v[i + 16];
      a[i] = mine + __shfl_xor(theirs, 16, 64);
    }
  }
  float b8[8];
  {
    bool hi = (lane & 8) != 0;
#pragma unroll
    for (int i = 0; i < 8; ++i) {
      float mine = hi ? a[i + 8] : a[i];
      float theirs = hi ? a[i] : a[i + 8];
      b8[i] = mine + __shfl_xor(theirs, 8, 64);
    }
  }
  float c4[4];
  {
    bool hi = (lane & 4) != 0;
#pragma unroll
    for (int i = 0; i < 4; ++i) {
      float mine = hi ? b8[i + 4] : b8[i];
      float theirs = hi ? b8[i] : b8[i + 4];
      c4[i] = mine + __shfl_xor(theirs, 4, 64);
    }
  }
  float d2[2];
  {
    bool hi = (lane & 2) != 0;
#pragma unroll
    for (int i = 0; i < 2; ++i) {
      float mine = hi ? c4[i + 2] : c4[i];
      float theirs = hi ? c4[i] : c4[i + 2];
      d2[i] = mine + __shfl_xor(theirs, 2, 64);
    }
  }
  {
    bool hi = (lane & 1) != 0;
    float mine = hi ? d2[1] : d2[0];
    float theirs = hi ? d2[0] : d2[1];
    return mine + __shfl_xor(theirs, 1, 64);
  }
}

// K_A: xs[b,n] = sum_f x[b,n,f]
__global__ __launch_bounds__(256) void k_prep(const float* __restrict__ x,
                                              float* __restrict__ xs) {
  int t = threadIdx.x;
  int row = blockIdx.x * 8 + (t >> 5);  // b*N + n
  float v = x[row * F + (t & 31)];
#pragma unroll
  for (int off = 16; off; off >>= 1) v += __shfl_down(v, off, 32);
  if ((t & 31) == 0) xs[row] = v;
}

// K_B: per-graph degree count in LDS -> dis = rsqrt(1 + cnt). One block/graph.
__global__ __launch_bounds__(256) void k_deg(const int* __restrict__ edges,
                                             float* __restrict__ dis) {
  __shared__ float cnt[N];
  int b = blockIdx.x, t = threadIdx.x;
#pragma unroll
  for (int i = 0; i < 4; ++i) cnt[t + i * 256] = 0.f;
  __syncthreads();
  const int* er = edges + b * 2 * E;
#pragma unroll 4
  for (int i = 0; i < E / 256; ++i) atomicAdd(&cnt[er[i * 256 + t]], 1.0f);
  __syncthreads();
#pragma unroll
  for (int i = 0; i < 4; ++i) {
    int j = t + i * 256;
    dis[(b << 10) + j] = rsqrtf(1.0f + cnt[j]);  // deg >= 1 always
  }
}

// K_C: g[b,row] = sum_edges dis[row]*dis[col]*xs[col] + xs[row]*dis[row]^2.
// One block/graph: dis,xs staged in LDS, g accumulated in LDS (ds_add_f32),
// non-atomic global flush. Also writes the ys tails of zx/zain.
__global__ __launch_bounds__(256) void k_scatter(const int* __restrict__ edges,
                                                 const float* __restrict__ dis,
                                                 const float* __restrict__ xs,
                                                 float* __restrict__ g,
                                                 const float* __restrict__ ys,
                                                 float* __restrict__ zx,
                                                 float* __restrict__ zain) {
  __shared__ float dl[N], xl[N], gl[N];
  int b = blockIdx.x, t = threadIdx.x;
#pragma unroll
  for (int i = 0; i < 4; ++i) {
    int j = t + i * 256;
    dl[j] = dis[(b << 10) + j];
    xl[j] = xs[(b << 10) + j];
    gl[j] = 0.f;
  }
  __syncthreads();
  const int* er = edges + b * 2 * E;
  const int* ec = er + E;
#pragma unroll 4
  for (int i = 0; i < E / 256; ++i) {
    int e = i * 256 + t;
    int row = er[e], col = ec[e];
    atomicAdd(&gl[row], dl[row] * dl[col] * xl[col]);
  }
  __syncthreads();
#pragma unroll
  for (int i = 0; i < 4; ++i) {
    int j = t + i * 256;
    g[(b << 10) + j] = gl[j] + xl[j] * dl[j] * dl[j];  // + self-loop term
  }
  if (t < C) {
    float v = ys[b * C + t];
    zx[b * NC + N + t] = v;
    zain[b * NC + N + t] = v;
  }
}

// K_D: s[b,n] = phi[b,n,:] . g[b,:]; epilogue: mu/logvar outputs + reparam
__global__ __launch_bounds__(256) void k_phimv(
    const float* __restrict__ phi, const float* __restrict__ g,
    const float* __restrict__ fx1, const float* __restrict__ fx2,
    const float* __restrict__ fa1, const float* __restrict__ fa2,
    const float* __restrict__ eps_x, const float* __restrict__ eps_a,
    float* __restrict__ xmu, float* __restrict__ xlv,
    float* __restrict__ amu, float* __restrict__ alv,
    float* __restrict__ zx, float* __restrict__ zain) {
  __shared__ float gl[N];
  int t = threadIdx.x;
  int row0 = blockIdx.x * 4;   // 4 waves, 4 consecutive rows, same b (N%4==0)
  int b = row0 >> 10;
#pragma unroll
  for (int i = 0; i < 4; ++i) gl[t + i * 256] = g[(b << 10) + t + i * 256];
  __syncthreads();
  int lane = t & 63;
  int row = row0 + (t >> 6);
  int n = row & (N - 1);
  const float* prow = phi + (size_t)row * N;
  float acc = 0.f;
#pragma unroll
  for (int i = 0; i < 4; ++i) {
    int m = i * 256 + lane * 4;
    float4 p = *reinterpret_cast<const float4*>(prow + m);
    acc += p.x * gl[m] + p.y * gl[m + 1] + p.z * gl[m + 2] + p.w * gl[m + 3];
  }
  acc = wave_sum(acc);
  if (lane == 0) {
    float s = acc;
    float v_xmu = fx1[n] * s, v_xlv = fx2[n] * s;
    float v_amu = fa1[n] * s, v_alv = fa2[n] * s;
    xmu[row] = v_xmu;
    xlv[row] = v_xlv;
    amu[row] = v_amu;
    alv[row] = v_alv;
    zx[b * NC + n] = v_xmu + eps_x[row] * expf(0.5f * v_xlv);
    zain[b * NC + n] = v_amu + eps_a[row] * expf(0.5f * v_alv);
  }
}

// K_E: za[b,n] = zain[b,:] . Wa[n,:] + ba[n]  (one wave per n, all 32 b)
__global__ __launch_bounds__(64) void k_za(const float* __restrict__ Wa,
                                           const float* __restrict__ ba,
                                           const float* __restrict__ zain,
                                           float* __restrict__ za) {
  int nidx = blockIdx.x;
  int lane = threadIdx.x;
  const float* wr = Wa + nidx * NC;
  float acc[32];
#pragma unroll
  for (int bb = 0; bb < 32; ++bb) acc[bb] = 0.f;
  for (int j = lane; j < NC; j += 64) {
    float w = wr[j];
#pragma unroll
    for (int bb = 0; bb < 32; ++bb) acc[bb] += w * zain[bb * NC + j];
  }
  float bav = ba[nidx];
  float r = reduce32_distribute(acc, lane);
  if (lane < 32) za[lane * N + nidx] = r + bav;
}

// K_F: recon_x[b,k] = sigmoid(zx[b,:] . Wx[k,:] + bx[k]); wave owns 4 k-rows.
// zx staged transposed in LDS ([jj][b], pad 33 -> 2-way bank alias, free), Wx coalesced.
__global__ __launch_bounds__(256) void k_recon_x(const float* __restrict__ Wx,
                                                 const float* __restrict__ bx,
                                                 const float* __restrict__ zx,
                                                 float* __restrict__ rx) {
  __shared__ float zt[256 * 33];  // 33.8 KB
  int t = threadIdx.x, lane = t & 63;
  int k0 = blockIdx.x * 16 + (t >> 6) * 4;
  float acc[4][32];
#pragma unroll
  for (int gi = 0; gi < 4; ++gi)
#pragma unroll
    for (int bb = 0; bb < 32; ++bb) acc[gi][bb] = 0.f;

  for (int j0 = 0; j0 < NC; j0 += 256) {
    __syncthreads();
    bool ok = (j0 + t) < NC;
#pragma unroll
    for (int bb = 0; bb < 32; ++bb)
      zt[t * 33 + bb] = ok ? zx[bb * NC + j0 + t] : 0.f;
    __syncthreads();
#pragma unroll
    for (int s = 0; s < 4; ++s) {
      int jj = s * 64 + lane;
      int j = j0 + jj;
      float w0 = 0.f, w1 = 0.f, w2 = 0.f, w3 = 0.f;
      if (j < NC) {
        w0 = Wx[(size_t)(k0 + 0) * NC + j];
        w1 = Wx[(size_t)(k0 + 1) * NC + j];
        w2 = Wx[(size_t)(k0 + 2) * NC + j];
        w3 = Wx[(size_t)(k0 + 3) * NC + j];
      }
      const float* zp = &zt[jj * 33];
#pragma unroll
      for (int bb = 0; bb < 32; ++bb) {
        float z = zp[bb];
        acc[0][bb] += w0 * z;
        acc[1][bb] += w1 * z;
        acc[2][bb] += w2 * z;
        acc[3][bb] += w3 * z;
      }
    }
  }
  float bxv[4] = {bx[k0], bx[k0 + 1], bx[k0 + 2], bx[k0 + 3]};
#pragma unroll
  for (int gi = 0; gi < 4; ++gi) {
    float r = reduce32_distribute(acc[gi], lane);
    if (lane < 32) {
      float val = r + bxv[gi];
      rx[(size_t)lane * NF + k0 + gi] = 1.f / (1.f + __expf(-val));
    }
  }
}

// K_G: recon_a[b,i,j] = sigmoid(za[b,i]*za[b,j]), float4 stores
__global__ __launch_bounds__(256) void k_recon_a(const float* __restrict__ za,
                                                 float* __restrict__ ra) {
  int idx = blockIdx.x * 256 + threadIdx.x;  // float4 index over B*N*N/4
  int b = idx >> 18;
  int rem = idx & ((1 << 18) - 1);
  int i = rem >> 8;
  int j4 = rem & 255;
  float zi = za[(b << 10) + i];
  float4 zj = reinterpret_cast<const float4*>(za)[(b << 8) + j4];
  float4 o;
  o.x = 1.f / (1.f + __expf(-zi * zj.x));
  o.y = 1.f / (1.f + __expf(-zi * zj.y));
  o.z = 1.f / (1.f + __expf(-zi * zj.z));
  o.w = 1.f / (1.f + __expf(-zi * zj.w));
  reinterpret_cast<float4*>(ra)[idx] = o;
}

extern "C" void kernel_launch(void* const* d_in, const int* in_sizes, int n_in,
                              void* d_out, int out_size, void* d_ws, size_t ws_size,
                              hipStream_t stream) {
  const float* x = (const float*)d_in[0];
  const float* phi = (const float*)d_in[1];
  const float* ys = (const float*)d_in[2];
  const float* fx1 = (const float*)d_in[3];
  const float* fx2 = (const float*)d_in[4];
  const float* fa1 = (const float*)d_in[5];
  const float* fa2 = (const float*)d_in[6];
  const float* Wx = (const float*)d_in[7];
  const float* bx = (const float*)d_in[8];
  const float* Wa = (const float*)d_in[9];
  const float* ba = (const float*)d_in[10];
  const float* epsx = (const float*)d_in[11];
  const float* epsa = (const float*)d_in[12];
  const int* edges = (const int*)d_in[13];

  float* out = (float*)d_out;
  float* rx = out;                    // [B,N,F]   1,048,576
  float* xmu = out + 1048576;         // [B,N]        32,768
  float* xlv = out + 1081344;         // [B,N]        32,768
  float* ra = out + 1114112;          // [B,N,N]  33,554,432
  float* amu = out + 34668544;        // [B,N]        32,768
  float* alv = out + 34701312;        // [B,N]        32,768

  float* ws = (float*)d_ws;
  float* xs = ws + WS_XS;
  float* dis = ws + WS_DIS;
  float* g = ws + WS_G;
  float* zx = ws + WS_ZX;
  float* zain = ws + WS_ZAIN;
  float* za = ws + WS_ZA;

  k_prep<<<B * N / 8, 256, 0, stream>>>(x, xs);
  k_deg<<<B, 256, 0, stream>>>(edges, dis);
  k_scatter<<<B, 256, 0, stream>>>(edges, dis, xs, g, ys, zx, zain);
  k_phimv<<<B * N / 4, 256, 0, stream>>>(phi, g, fx1, fx2, fa1, fa2, epsx, epsa,
                                         xmu, xlv, amu, alv, zx, zain);
  k_za<<<N, 64, 0, stream>>>(Wa, ba, zain, za);
  k_recon_x<<<NF / 16, 256, 0, stream>>>(Wx, bx, zx, rx);
  k_recon_a<<<B * N * N / 4 / 256, 256, 0, stream>>>(za, ra);
}

// Round 4
// 573.027 us; speedup vs baseline: 1.1615x; 1.1615x over previous
//
#include <hip/hip_runtime.h>

#define B 32
#define N 1024
#define E 32768
#define F 32
#define C 10
#define NC (N + C)   // 1034
#define NF (N * F)   // 32768

// ws layout (float offsets)
#define WS_XS    0
#define WS_DIS   32768
#define WS_G     65536
#define WS_ZX    98304
#define WS_ZAIN  131392
#define WS_ZA    164480
// total 197248 floats = 771 KB

__device__ __forceinline__ float wave_sum(float v) {
#pragma unroll
  for (int off = 32; off; off >>= 1) v += __shfl_xor(v, off, 64);
  return v;
}

__device__ __forceinline__ float fast_sigmoid(float x) {
  return __builtin_amdgcn_rcpf(1.f + __expf(-x));  // v_rcp_f32, ~1ulp, post-sigmoid noise
}

// Reduce 32 per-lane partial arrays across 64 lanes; lane l (and l+32) returns
// the full sum for b = (l & 31). All indices compile-time (no scratch).
__device__ __forceinline__ float reduce32_distribute(float (&v)[32], int lane) {
#pragma unroll
  for (int i = 0; i < 32; ++i) v[i] += __shfl_xor(v[i], 32, 64);
  float a[16];
  {
    bool hi = (lane & 16) != 0;
#pragma unroll
    for (int i = 0; i < 16; ++i) {
      float mine = hi ? v[i + 16] : v[i];
      float theirs = hi ? v[i] : v[i + 16];
      a[i] = mine + __shfl_xor(theirs, 16, 64);
    }
  }
  float b8[8];
  {
    bool hi = (lane & 8) != 0;
#pragma unroll
    for (int i = 0; i < 8; ++i) {
      float mine = hi ? a[i + 8] : a[i];
      float theirs = hi ? a[i] : a[i + 8];
      b8[i] = mine + __shfl_xor(theirs, 8, 64);
    }
  }
  float c4[4];
  {
    bool hi = (lane & 4) != 0;
#pragma unroll
    for (int i = 0; i < 4; ++i) {
      float mine = hi ? b8[i + 4] : b8[i];
      float theirs = hi ? b8[i] : b8[i + 4];
      c4[i] = mine + __shfl_xor(theirs, 4, 64);
    }
  }
  float d2[2];
  {
    bool hi = (lane & 2) != 0;
#pragma unroll
    for (int i = 0; i < 2; ++i) {
      float mine = hi ? c4[i + 2] : c4[i];
      float theirs = hi ? c4[i] : c4[i + 2];
      d2[i] = mine + __shfl_xor(theirs, 2, 64);
    }
  }
  {
    bool hi = (lane & 1) != 0;
    float mine = hi ? d2[1] : d2[0];
    float theirs = hi ? d2[0] : d2[1];
    return mine + __shfl_xor(theirs, 1, 64);
  }
}

// K_A: xs[b,n] = sum_f x[b,n,f]
__global__ __launch_bounds__(256) void k_prep(const float* __restrict__ x,
                                              float* __restrict__ xs) {
  int t = threadIdx.x;
  int row = blockIdx.x * 8 + (t >> 5);  // b*N + n
  float v = x[row * F + (t & 31)];
#pragma unroll
  for (int off = 16; off; off >>= 1) v += __shfl_down(v, off, 32);
  if ((t & 31) == 0) xs[row] = v;
}

// K_B: per-graph degree count in LDS -> dis = rsqrt(1 + cnt). One block/graph.
__global__ __launch_bounds__(256) void k_deg(const int* __restrict__ edges,
                                             float* __restrict__ dis) {
  __shared__ float cnt[N];
  int b = blockIdx.x, t = threadIdx.x;
#pragma unroll
  for (int i = 0; i < 4; ++i) cnt[t + i * 256] = 0.f;
  __syncthreads();
  const int* er = edges + b * 2 * E;
#pragma unroll 4
  for (int i = 0; i < E / 256; ++i) atomicAdd(&cnt[er[i * 256 + t]], 1.0f);
  __syncthreads();
#pragma unroll
  for (int i = 0; i < 4; ++i) {
    int j = t + i * 256;
    dis[(b << 10) + j] = rsqrtf(1.0f + cnt[j]);  // deg >= 1 always
  }
}

// K_C: g[b,row] = sum_edges dis[row]*dis[col]*xs[col] + xs[row]*dis[row]^2.
// One block/graph: dis,xs staged in LDS, g accumulated in LDS (ds_add_f32),
// non-atomic global flush. Also writes the ys tails of zx/zain.
__global__ __launch_bounds__(256) void k_scatter(const int* __restrict__ edges,
                                                 const float* __restrict__ dis,
                                                 const float* __restrict__ xs,
                                                 float* __restrict__ g,
                                                 const float* __restrict__ ys,
                                                 float* __restrict__ zx,
                                                 float* __restrict__ zain) {
  __shared__ float dl[N], xl[N], gl[N];
  int b = blockIdx.x, t = threadIdx.x;
#pragma unroll
  for (int i = 0; i < 4; ++i) {
    int j = t + i * 256;
    dl[j] = dis[(b << 10) + j];
    xl[j] = xs[(b << 10) + j];
    gl[j] = 0.f;
  }
  __syncthreads();
  const int* er = edges + b * 2 * E;
  const int* ec = er + E;
#pragma unroll 4
  for (int i = 0; i < E / 256; ++i) {
    int e = i * 256 + t;
    int row = er[e], col = ec[e];
    atomicAdd(&gl[row], dl[row] * dl[col] * xl[col]);
  }
  __syncthreads();
#pragma unroll
  for (int i = 0; i < 4; ++i) {
    int j = t + i * 256;
    g[(b << 10) + j] = gl[j] + xl[j] * dl[j] * dl[j];  // + self-loop term
  }
  if (t < C) {
    float v = ys[b * C + t];
    zx[b * NC + N + t] = v;
    zain[b * NC + N + t] = v;
  }
}

// K_D: s[b,n] = phi[b,n,:] . g[b,:]; epilogue: mu/logvar outputs + reparam
__global__ __launch_bounds__(256) void k_phimv(
    const float* __restrict__ phi, const float* __restrict__ g,
    const float* __restrict__ fx1, const float* __restrict__ fx2,
    const float* __restrict__ fa1, const float* __restrict__ fa2,
    const float* __restrict__ eps_x, const float* __restrict__ eps_a,
    float* __restrict__ xmu, float* __restrict__ xlv,
    float* __restrict__ amu, float* __restrict__ alv,
    float* __restrict__ zx, float* __restrict__ zain) {
  __shared__ float gl[N];
  int t = threadIdx.x;
  int row0 = blockIdx.x * 4;   // 4 waves, 4 consecutive rows, same b (N%4==0)
  int b = row0 >> 10;
#pragma unroll
  for (int i = 0; i < 4; ++i) gl[t + i * 256] = g[(b << 10) + t + i * 256];
  __syncthreads();
  int lane = t & 63;
  int row = row0 + (t >> 6);
  int n = row & (N - 1);
  const float* prow = phi + (size_t)row * N;
  float acc = 0.f;
#pragma unroll
  for (int i = 0; i < 4; ++i) {
    int m = i * 256 + lane * 4;
    float4 p = *reinterpret_cast<const float4*>(prow + m);
    acc += p.x * gl[m] + p.y * gl[m + 1] + p.z * gl[m + 2] + p.w * gl[m + 3];
  }
  acc = wave_sum(acc);
  if (lane == 0) {
    float s = acc;
    float v_xmu = fx1[n] * s, v_xlv = fx2[n] * s;
    float v_amu = fa1[n] * s, v_alv = fa2[n] * s;
    xmu[row] = v_xmu;
    xlv[row] = v_xlv;
    amu[row] = v_amu;
    alv[row] = v_alv;
    zx[b * NC + n] = v_xmu + eps_x[row] * expf(0.5f * v_xlv);
    zain[b * NC + n] = v_amu + eps_a[row] * expf(0.5f * v_alv);
  }
}

// K_E: za[b,n] = zain[b,:] . Wa[n,:] + ba[n]  (one wave per n, all 32 b)
__global__ __launch_bounds__(64) void k_za(const float* __restrict__ Wa,
                                           const float* __restrict__ ba,
                                           const float* __restrict__ zain,
                                           float* __restrict__ za) {
  int nidx = blockIdx.x;
  int lane = threadIdx.x;
  const float* wr = Wa + nidx * NC;
  float acc[32];
#pragma unroll
  for (int bb = 0; bb < 32; ++bb) acc[bb] = 0.f;
  for (int j = lane; j < NC; j += 64) {
    float w = wr[j];
#pragma unroll
    for (int bb = 0; bb < 32; ++bb) acc[bb] += w * zain[bb * NC + j];
  }
  float bav = ba[nidx];
  float r = reduce32_distribute(acc, lane);
  if (lane < 32) za[lane * N + nidx] = r + bav;
}

// K_F: recon_x[b,k] = sigmoid(zx[b,:] . Wx[k,:] + bx[k]); wave owns 4 k-rows.
// Per 256-wide j-chunk: stage zt (conflict-free (t+bb)%32 layout), prefetch ALL
// 16 Wx values into regs BEFORE the compute loop (4 KB in flight/wave — covers
// ~900cy HBM latency), guard-free main loop; 10-elem tail handled separately.
__global__ __launch_bounds__(256, 3) void k_recon_x(const float* __restrict__ Wx,
                                                    const float* __restrict__ bx,
                                                    const float* __restrict__ zx,
                                                    float* __restrict__ rx) {
  __shared__ float zt[256 * 33];  // 33.8 KB
  int t = threadIdx.x, lane = t & 63;
  int k0 = blockIdx.x * 16 + (t >> 6) * 4;
  float acc[4][32];
#pragma unroll
  for (int gi = 0; gi < 4; ++gi)
#pragma unroll
    for (int bb = 0; bb < 32; ++bb) acc[gi][bb] = 0.f;

#pragma unroll 1
  for (int c = 0; c < 4; ++c) {  // 4 full 256-wide chunks (j = 0..1023)
    int j0 = c * 256;
    __syncthreads();  // prior chunk's zt reads complete
#pragma unroll
    for (int bb = 0; bb < 32; ++bb)
      zt[t * 33 + bb] = zx[bb * NC + j0 + t];
    // Wx prefetch for this chunk: 16 independent coalesced loads in flight
    float w[4][4];
#pragma unroll
    for (int s = 0; s < 4; ++s)
#pragma unroll
      for (int gi = 0; gi < 4; ++gi)
        w[s][gi] = Wx[(size_t)(k0 + gi) * NC + j0 + s * 64 + lane];
    __syncthreads();  // zt ready
#pragma unroll
    for (int s = 0; s < 4; ++s) {
      const float* zp = &zt[(s * 64 + lane) * 33];
#pragma unroll
      for (int bb = 0; bb < 32; ++bb) {
        float z = zp[bb];
        acc[0][bb] += w[s][0] * z;
        acc[1][bb] += w[s][1] * z;
        acc[2][bb] += w[s][2] * z;
        acc[3][bb] += w[s][3] * z;
      }
    }
  }
  // tail: j = 1024..1033 (10 values)
  __syncthreads();
  if (t < 10) {
#pragma unroll
    for (int bb = 0; bb < 32; ++bb) zt[t * 33 + bb] = zx[bb * NC + 1024 + t];
  }
  __syncthreads();
  if (lane < 10) {
    float wt[4];
#pragma unroll
    for (int gi = 0; gi < 4; ++gi) wt[gi] = Wx[(size_t)(k0 + gi) * NC + 1024 + lane];
    const float* zp = &zt[lane * 33];
#pragma unroll
    for (int bb = 0; bb < 32; ++bb) {
      float z = zp[bb];
      acc[0][bb] += wt[0] * z;
      acc[1][bb] += wt[1] * z;
      acc[2][bb] += wt[2] * z;
      acc[3][bb] += wt[3] * z;
    }
  }

  float bxv[4] = {bx[k0], bx[k0 + 1], bx[k0 + 2], bx[k0 + 3]};
#pragma unroll
  for (int gi = 0; gi < 4; ++gi) {
    float r = reduce32_distribute(acc[gi], lane);
    if (lane < 32) {
      rx[(size_t)lane * NF + k0 + gi] = fast_sigmoid(r + bxv[gi]);
    }
  }
}

// K_G: recon_a[b,i,j] = sigmoid(za[b,i]*za[b,j]), float4 stores
__global__ __launch_bounds__(256) void k_recon_a(const float* __restrict__ za,
                                                 float* __restrict__ ra) {
  int idx = blockIdx.x * 256 + threadIdx.x;  // float4 index over B*N*N/4
  int b = idx >> 18;
  int rem = idx & ((1 << 18) - 1);
  int i = rem >> 8;
  int j4 = rem & 255;
  float zi = za[(b << 10) + i];
  float4 zj = reinterpret_cast<const float4*>(za)[(b << 8) + j4];
  float4 o;
  o.x = fast_sigmoid(zi * zj.x);
  o.y = fast_sigmoid(zi * zj.y);
  o.z = fast_sigmoid(zi * zj.z);
  o.w = fast_sigmoid(zi * zj.w);
  reinterpret_cast<float4*>(ra)[idx] = o;
}

extern "C" void kernel_launch(void* const* d_in, const int* in_sizes, int n_in,
                              void* d_out, int out_size, void* d_ws, size_t ws_size,
                              hipStream_t stream) {
  const float* x = (const float*)d_in[0];
  const float* phi = (const float*)d_in[1];
  const float* ys = (const float*)d_in[2];
  const float* fx1 = (const float*)d_in[3];
  const float* fx2 = (const float*)d_in[4];
  const float* fa1 = (const float*)d_in[5];
  const float* fa2 = (const float*)d_in[6];
  const float* Wx = (const float*)d_in[7];
  const float* bx = (const float*)d_in[8];
  const float* Wa = (const float*)d_in[9];
  const float* ba = (const float*)d_in[10];
  const float* epsx = (const float*)d_in[11];
  const float* epsa = (const float*)d_in[12];
  const int* edges = (const int*)d_in[13];

  float* out = (float*)d_out;
  float* rx = out;                    // [B,N,F]   1,048,576
  float* xmu = out + 1048576;         // [B,N]        32,768
  float* xlv = out + 1081344;         // [B,N]        32,768
  float* ra = out + 1114112;          // [B,N,N]  33,554,432
  float* amu = out + 34668544;        // [B,N]        32,768
  float* alv = out + 34701312;        // [B,N]        32,768

  float* ws = (float*)d_ws;
  float* xs = ws + WS_XS;
  float* dis = ws + WS_DIS;
  float* g = ws + WS_G;
  float* zx = ws + WS_ZX;
  float* zain = ws + WS_ZAIN;
  float* za = ws + WS_ZA;

  k_prep<<<B * N / 8, 256, 0, stream>>>(x, xs);
  k_deg<<<B, 256, 0, stream>>>(edges, dis);
  k_scatter<<<B, 256, 0, stream>>>(edges, dis, xs, g, ys, zx, zain);
  k_phimv<<<B * N / 4, 256, 0, stream>>>(phi, g, fx1, fx2, fa1, fa2, epsx, epsa,
                                         xmu, xlv, amu, alv, zx, zain);
  k_za<<<N, 64, 0, stream>>>(Wa, ba, zain, za);
  k_recon_x<<<NF / 16, 256, 0, stream>>>(Wx, bx, zx, rx);
  k_recon_a<<<B * N * N / 4 / 256, 256, 0, stream>>>(za, ra);
}

// Round 6
// 569.264 us; speedup vs baseline: 1.1692x; 1.0066x over previous
//
#include <hip/hip_runtime.h>

#define B 32
#define N 1024
#define E 32768
#define F 32
#define C 10
#define NC (N + C)   // 1034
#define NF (N * F)   // 32768

// ws layout (float offsets)
#define WS_XS    0
#define WS_DIS   32768
#define WS_G     65536
#define WS_ZX    98304
#define WS_ZAIN  131392
#define WS_ZA    164480
// total 197248 floats = 771 KB

__device__ __forceinline__ float wave_sum(float v) {
#pragma unroll
  for (int off = 32; off; off >>= 1) v += __shfl_xor(v, off, 64);
  return v;
}

__device__ __forceinline__ float fast_sigmoid(float x) {
  return __builtin_amdgcn_rcpf(1.f + __expf(-x));  // v_rcp_f32, ~1ulp, post-sigmoid noise
}

// Reduce 32 per-lane partial arrays across 64 lanes; lane l (and l+32) returns
// the full sum for b = (l & 31). All indices compile-time (no scratch).
__device__ __forceinline__ float reduce32_distribute(float (&v)[32], int lane) {
#pragma unroll
  for (int i = 0; i < 32; ++i) v[i] += __shfl_xor(v[i], 32, 64);
  float a[16];
  {
    bool hi = (lane & 16) != 0;
#pragma unroll
    for (int i = 0; i < 16; ++i) {
      float mine = hi ? v[i + 16] : v[i];
      float theirs = hi ? v[i] : v[i + 16];
      a[i] = mine + __shfl_xor(theirs, 16, 64);
    }
  }
  float b8[8];
  {
    bool hi = (lane & 8) != 0;
#pragma unroll
    for (int i = 0; i < 8; ++i) {
      float mine = hi ? a[i + 8] : a[i];
      float theirs = hi ? a[i] : a[i + 8];
      b8[i] = mine + __shfl_xor(theirs, 8, 64);
    }
  }
  float c4[4];
  {
    bool hi = (lane & 4) != 0;
#pragma unroll
    for (int i = 0; i < 4; ++i) {
      float mine = hi ? b8[i + 4] : b8[i];
      float theirs = hi ? b8[i] : b8[i + 4];
      c4[i] = mine + __shfl_xor(theirs, 4, 64);
    }
  }
  float d2[2];
  {
    bool hi = (lane & 2) != 0;
#pragma unroll
    for (int i = 0; i < 2; ++i) {
      float mine = hi ? c4[i + 2] : c4[i];
      float theirs = hi ? c4[i] : c4[i + 2];
      d2[i] = mine + __shfl_xor(theirs, 2, 64);
    }
  }
  {
    bool hi = (lane & 1) != 0;
    float mine = hi ? d2[1] : d2[0];
    float theirs = hi ? d2[0] : d2[1];
    return mine + __shfl_xor(theirs, 1, 64);
  }
}

// K_A: xs[b,n] = sum_f x[b,n,f]
__global__ __launch_bounds__(256) void k_prep(const float* __restrict__ x,
                                              float* __restrict__ xs) {
  int t = threadIdx.x;
  int row = blockIdx.x * 8 + (t >> 5);  // b*N + n
  float v = x[row * F + (t & 31)];
#pragma unroll
  for (int off = 16; off; off >>= 1) v += __shfl_down(v, off, 32);
  if ((t & 31) == 0) xs[row] = v;
}

// K_B: per-graph degree count in LDS -> dis = rsqrt(1 + cnt). One block/graph.
__global__ __launch_bounds__(256) void k_deg(const int* __restrict__ edges,
                                             float* __restrict__ dis) {
  __shared__ float cnt[N];
  int b = blockIdx.x, t = threadIdx.x;
#pragma unroll
  for (int i = 0; i < 4; ++i) cnt[t + i * 256] = 0.f;
  __syncthreads();
  const int* er = edges + b * 2 * E;
#pragma unroll 4
  for (int i = 0; i < E / 256; ++i) atomicAdd(&cnt[er[i * 256 + t]], 1.0f);
  __syncthreads();
#pragma unroll
  for (int i = 0; i < 4; ++i) {
    int j = t + i * 256;
    dis[(b << 10) + j] = rsqrtf(1.0f + cnt[j]);  // deg >= 1 always
  }
}

// K_C: g[b,row] = sum_edges dis[row]*dis[col]*xs[col] + xs[row]*dis[row]^2.
// One block/graph: dis,xs staged in LDS, g accumulated in LDS (ds_add_f32),
// non-atomic global flush. Also writes the ys tails of zx/zain.
__global__ __launch_bounds__(256) void k_scatter(const int* __restrict__ edges,
                                                 const float* __restrict__ dis,
                                                 const float* __restrict__ xs,
                                                 float* __restrict__ g,
                                                 const float* __restrict__ ys,
                                                 float* __restrict__ zx,
                                                 float* __restrict__ zain) {
  __shared__ float dl[N], xl[N], gl[N];
  int b = blockIdx.x, t = threadIdx.x;
#pragma unroll
  for (int i = 0; i < 4; ++i) {
    int j = t + i * 256;
    dl[j] = dis[(b << 10) + j];
    xl[j] = xs[(b << 10) + j];
    gl[j] = 0.f;
  }
  __syncthreads();
  const int* er = edges + b * 2 * E;
  const int* ec = er + E;
#pragma unroll 4
  for (int i = 0; i < E / 256; ++i) {
    int e = i * 256 + t;
    int row = er[e], col = ec[e];
    atomicAdd(&gl[row], dl[row] * dl[col] * xl[col]);
  }
  __syncthreads();
#pragma unroll
  for (int i = 0; i < 4; ++i) {
    int j = t + i * 256;
    g[(b << 10) + j] = gl[j] + xl[j] * dl[j] * dl[j];  // + self-loop term
  }
  if (t < C) {
    float v = ys[b * C + t];
    zx[b * NC + N + t] = v;
    zain[b * NC + N + t] = v;
  }
}

// K_D: s[b,n] = phi[b,n,:] . g[b,:]; epilogue: mu/logvar outputs + reparam
__global__ __launch_bounds__(256) void k_phimv(
    const float* __restrict__ phi, const float* __restrict__ g,
    const float* __restrict__ fx1, const float* __restrict__ fx2,
    const float* __restrict__ fa1, const float* __restrict__ fa2,
    const float* __restrict__ eps_x, const float* __restrict__ eps_a,
    float* __restrict__ xmu, float* __restrict__ xlv,
    float* __restrict__ amu, float* __restrict__ alv,
    float* __restrict__ zx, float* __restrict__ zain) {
  __shared__ float gl[N];
  int t = threadIdx.x;
  int row0 = blockIdx.x * 4;   // 4 waves, 4 consecutive rows, same b (N%4==0)
  int b = row0 >> 10;
#pragma unroll
  for (int i = 0; i < 4; ++i) gl[t + i * 256] = g[(b << 10) + t + i * 256];
  __syncthreads();
  int lane = t & 63;
  int row = row0 + (t >> 6);
  int n = row & (N - 1);
  const float* prow = phi + (size_t)row * N;
  float acc = 0.f;
#pragma unroll
  for (int i = 0; i < 4; ++i) {
    int m = i * 256 + lane * 4;
    float4 p = *reinterpret_cast<const float4*>(prow + m);
    acc += p.x * gl[m] + p.y * gl[m + 1] + p.z * gl[m + 2] + p.w * gl[m + 3];
  }
  acc = wave_sum(acc);
  if (lane == 0) {
    float s = acc;
    float v_xmu = fx1[n] * s, v_xlv = fx2[n] * s;
    float v_amu = fa1[n] * s, v_alv = fa2[n] * s;
    xmu[row] = v_xmu;
    xlv[row] = v_xlv;
    amu[row] = v_amu;
    alv[row] = v_alv;
    zx[b * NC + n] = v_xmu + eps_x[row] * expf(0.5f * v_xlv);
    zain[b * NC + n] = v_amu + eps_a[row] * expf(0.5f * v_alv);
  }
}

// K_E: za[b,n] = zain[b,:] . Wa[n,:] + ba[n]  (one wave per n, all 32 b)
__global__ __launch_bounds__(64) void k_za(const float* __restrict__ Wa,
                                           const float* __restrict__ ba,
                                           const float* __restrict__ zain,
                                           float* __restrict__ za) {
  int nidx = blockIdx.x;
  int lane = threadIdx.x;
  const float* wr = Wa + nidx * NC;
  float acc[32];
#pragma unroll
  for (int bb = 0; bb < 32; ++bb) acc[bb] = 0.f;
  for (int j = lane; j < NC; j += 64) {
    float w = wr[j];
#pragma unroll
    for (int bb = 0; bb < 32; ++bb) acc[bb] += w * zain[bb * NC + j];
  }
  float bav = ba[nidx];
  float r = reduce32_distribute(acc, lane);
  if (lane < 32) za[lane * N + nidx] = r + bav;
}

// K_F: recon_x[b,k] = sigmoid(zx[b,:] . Wx[k,:] + bx[k]); wave owns 4 k-rows.
// Per 256-wide j-chunk: stage zt (stride-33 layout, conflict-free), prefetch ALL
// 16 Wx values into regs BEFORE the compute loop (4 KB in flight/wave — covers
// ~900cy HBM latency). NO min-waves clamp: acc[4][32]+w[4][4] needs ~170 VGPR;
// round-4's (256,3) bound forced spills (VGPR 84, 50 MB scratch writes).
__global__ __launch_bounds__(256) void k_recon_x(const float* __restrict__ Wx,
                                                 const float* __restrict__ bx,
                                                 const float* __restrict__ zx,
                                                 float* __restrict__ rx) {
  __shared__ float zt[256 * 33];  // 33.8 KB
  int t = threadIdx.x, lane = t & 63;
  int k0 = blockIdx.x * 16 + (t >> 6) * 4;
  float acc[4][32];
#pragma unroll
  for (int gi = 0; gi < 4; ++gi)
#pragma unroll
    for (int bb = 0; bb < 32; ++bb) acc[gi][bb] = 0.f;

#pragma unroll 1
  for (int c = 0; c < 4; ++c) {  // 4 full 256-wide chunks (j = 0..1023)
    int j0 = c * 256;
    __syncthreads();  // prior chunk's zt reads complete
#pragma unroll
    for (int bb = 0; bb < 32; ++bb)
      zt[t * 33 + bb] = zx[bb * NC + j0 + t];
    // Wx prefetch for this chunk: 16 independent coalesced loads in flight
    float w[4][4];
#pragma unroll
    for (int s = 0; s < 4; ++s)
#pragma unroll
      for (int gi = 0; gi < 4; ++gi)
        w[s][gi] = Wx[(size_t)(k0 + gi) * NC + j0 + s * 64 + lane];
    __syncthreads();  // zt ready
#pragma unroll
    for (int s = 0; s < 4; ++s) {
      const float* zp = &zt[(s * 64 + lane) * 33];
#pragma unroll
      for (int bb = 0; bb < 32; ++bb) {
        float z = zp[bb];
        acc[0][bb] += w[s][0] * z;
        acc[1][bb] += w[s][1] * z;
        acc[2][bb] += w[s][2] * z;
        acc[3][bb] += w[s][3] * z;
      }
    }
  }
  // tail: j = 1024..1033 (10 values)
  __syncthreads();
  if (t < 10) {
#pragma unroll
    for (int bb = 0; bb < 32; ++bb) zt[t * 33 + bb] = zx[bb * NC + 1024 + t];
  }
  __syncthreads();
  if (lane < 10) {
    float wt[4];
#pragma unroll
    for (int gi = 0; gi < 4; ++gi) wt[gi] = Wx[(size_t)(k0 + gi) * NC + 1024 + lane];
    const float* zp = &zt[lane * 33];
#pragma unroll
    for (int bb = 0; bb < 32; ++bb) {
      float z = zp[bb];
      acc[0][bb] += wt[0] * z;
      acc[1][bb] += wt[1] * z;
      acc[2][bb] += wt[2] * z;
      acc[3][bb] += wt[3] * z;
    }
  }

  float bxv[4] = {bx[k0], bx[k0 + 1], bx[k0 + 2], bx[k0 + 3]};
#pragma unroll
  for (int gi = 0; gi < 4; ++gi) {
    float r = reduce32_distribute(acc[gi], lane);
    if (lane < 32) {
      rx[(size_t)lane * NF + k0 + gi] = fast_sigmoid(r + bxv[gi]);
    }
  }
}

// K_G: recon_a[b,i,j] = sigmoid(za[b,i]*za[b,j]), float4 stores
__global__ __launch_bounds__(256) void k_recon_a(const float* __restrict__ za,
                                                 float* __restrict__ ra) {
  int idx = blockIdx.x * 256 + threadIdx.x;  // float4 index over B*N*N/4
  int b = idx >> 18;
  int rem = idx & ((1 << 18) - 1);
  int i = rem >> 8;
  int j4 = rem & 255;
  float zi = za[(b << 10) + i];
  float4 zj = reinterpret_cast<const float4*>(za)[(b << 8) + j4];
  float4 o;
  o.x = fast_sigmoid(zi * zj.x);
  o.y = fast_sigmoid(zi * zj.y);
  o.z = fast_sigmoid(zi * zj.z);
  o.w = fast_sigmoid(zi * zj.w);
  reinterpret_cast<float4*>(ra)[idx] = o;
}

extern "C" void kernel_launch(void* const* d_in, const int* in_sizes, int n_in,
                              void* d_out, int out_size, void* d_ws, size_t ws_size,
                              hipStream_t stream) {
  const float* x = (const float*)d_in[0];
  const float* phi = (const float*)d_in[1];
  const float* ys = (const float*)d_in[2];
  const float* fx1 = (const float*)d_in[3];
  const float* fx2 = (const float*)d_in[4];
  const float* fa1 = (const float*)d_in[5];
  const float* fa2 = (const float*)d_in[6];
  const float* Wx = (const float*)d_in[7];
  const float* bx = (const float*)d_in[8];
  const float* Wa = (const float*)d_in[9];
  const float* ba = (const float*)d_in[10];
  const float* epsx = (const float*)d_in[11];
  const float* epsa = (const float*)d_in[12];
  const int* edges = (const int*)d_in[13];

  float* out = (float*)d_out;
  float* rx = out;                    // [B,N,F]   1,048,576
  float* xmu = out + 1048576;         // [B,N]        32,768
  float* xlv = out + 1081344;         // [B,N]        32,768
  float* ra = out + 1114112;          // [B,N,N]  33,554,432
  float* amu = out + 34668544;        // [B,N]        32,768
  float* alv = out + 34701312;        // [B,N]        32,768

  float* ws = (float*)d_ws;
  float* xs = ws + WS_XS;
  float* dis = ws + WS_DIS;
  float* g = ws + WS_G;
  float* zx = ws + WS_ZX;
  float* zain = ws + WS_ZAIN;
  float* za = ws + WS_ZA;

  k_prep<<<B * N / 8, 256, 0, stream>>>(x, xs);
  k_deg<<<B, 256, 0, stream>>>(edges, dis);
  k_scatter<<<B, 256, 0, stream>>>(edges, dis, xs, g, ys, zx, zain);
  k_phimv<<<B * N / 4, 256, 0, stream>>>(phi, g, fx1, fx2, fa1, fa2, epsx, epsa,
                                         xmu, xlv, amu, alv, zx, zain);
  k_za<<<N, 64, 0, stream>>>(Wa, ba, zain, za);
  k_recon_x<<<NF / 16, 256, 0, stream>>>(Wx, bx, zx, rx);
  k_recon_a<<<B * N * N / 4 / 256, 256, 0, stream>>>(za, ra);
}